// Round 1
// baseline (326.456 us; speedup 1.0000x reference)
//
#include <hip/hip_runtime.h>

// Problem constants
constexpr int B_ = 2, D_ = 8, H_ = 64, W_ = 64, C_ = 96;
constexpr int NH_ = 4, HD_ = 24;         // heads, head dim
constexpr int WC   = W_ * C_;            // 6144
constexpr int HWC  = H_ * W_ * C_;       // 393216
constexpr int BDHWC = B_ * D_ * HWC;     // 6291456
constexpr int NTOK = 128;                // tokens per window (64 h x 2 w)
constexpr float SCALE = 0.10206207261596577f;  // (384/4)^-0.5

constexpr int NTHR = 512;

// LDS layout (float offsets)
constexpr int OFF_K  = 0;                 // 128*96 = 12288
constexpr int OFF_V  = 12288;             // 128*96 = 12288
constexpr int OFF_O  = 24576;             // 128*100 = 12800 (pad stride 100)
constexpr int OFF_CW = 37376;             // 2592 conv weights
constexpr int OFF_CB = 39968;             // 96
constexpr int OFF_PB = 40064;             // 96
constexpr int LDS_FLOATS = 40160;         // 160,640 bytes

__global__ void __launch_bounds__(NTHR, 1)
sst_attn_kernel(const float* __restrict__ qkv, const float* __restrict__ cw,
                const float* __restrict__ cb, const float* __restrict__ pw,
                const float* __restrict__ pb, float* __restrict__ out) {
  extern __shared__ float lds[];
  float* sK  = lds + OFF_K;
  float* sV  = lds + OFF_V;
  float* sO  = lds + OFF_O;   // stride 100 per token row
  float* sCW = lds + OFF_CW;
  float* sCB = lds + OFF_CB;
  float* sPB = lds + OFF_PB;
  float* sPWT = lds + OFF_K;  // transposed proj_w, reuses K region after attention

  const int t   = threadIdx.x;
  const int bid = blockIdx.x;
  const int wq  = bid & 31;          // which pair of W columns
  const int d   = (bid >> 5) & 7;
  const int b   = bid >> 8;

  const float* qpl = qkv + (size_t)(b * D_ + d) * HWC;   // q plane (b,d)
  const float* kpl = qpl + BDHWC;
  const float* vpl = kpl + BDHWC;
  const float* vbb = qkv + 2 * (size_t)BDHWC + (size_t)b * D_ * HWC;  // v batch base

  // ---------------- stage K, V windows + small tensors ----------------
  {
    const int rowoff = wq * 192;   // 2 W-columns * 96 channels, contiguous per h
    float4* k4 = reinterpret_cast<float4*>(sK);
    float4* v4 = reinterpret_cast<float4*>(sV);
    #pragma unroll
    for (int it = 0; it < 6; ++it) {
      int i = t + it * NTHR;           // 3072 float4 total
      int fo = i << 2;                  // float offset, = h*192 + rem
      int h = fo / 192;
      int rem = fo - h * 192;
      int g = h * WC + rowoff + rem;
      k4[i] = *reinterpret_cast<const float4*>(kpl + g);
      v4[i] = *reinterpret_cast<const float4*>(vpl + g);
    }
    for (int i = t; i < 2592; i += NTHR) sCW[i] = cw[i];
    if (t < 96) { sCB[t] = cb[t]; sPB[t] = pb[t]; }
  }

  // ---------------- load this lane's q row (registers) ----------------
  const int wave = t >> 6, lane = t & 63;
  const int head = wave >> 1;
  const int n    = lane + ((wave & 1) << 6);   // token row owned by this lane
  const int hc   = head * HD_;
  const int tok_g = (n >> 1) * WC + (wq * 2 + (n & 1)) * C_;  // plane offset of token

  float qr[24];
  {
    const float4* q4 = reinterpret_cast<const float4*>(qpl + tok_g + hc);
    #pragma unroll
    for (int j = 0; j < 6; ++j) {
      float4 x = q4[j];
      qr[j*4+0] = x.x * SCALE; qr[j*4+1] = x.y * SCALE;
      qr[j*4+2] = x.z * SCALE; qr[j*4+3] = x.w * SCALE;
    }
  }

  __syncthreads();   // sK/sV/sCW/sCB staged

  // ---------------- LePE: depthwise 3x3x3 conv from global v ----------------
  #pragma unroll 1
  for (int idx = t; idx < NTOK * C_; idx += NTHR) {
    int nn = idx / 96;
    int c  = idx - nn * 96;
    int h  = nn >> 1;
    int w  = wq * 2 + (nn & 1);
    float a = sCB[c];
    const float* wc_ = sCW + c * 27;
    #pragma unroll
    for (int dd = 0; dd < 3; ++dd) {
      int zd = d + dd - 1;
      if (zd < 0 || zd >= D_) continue;
      #pragma unroll
      for (int dh = 0; dh < 3; ++dh) {
        int zh = h + dh - 1;
        if (zh < 0 || zh >= H_) continue;
        #pragma unroll
        for (int dw = 0; dw < 3; ++dw) {
          int zw = w + dw - 1;
          if (zw < 0 || zw >= W_) continue;
          a = fmaf(vbb[(size_t)zd * HWC + zh * WC + zw * C_ + c],
                   wc_[dd * 9 + dh * 3 + dw], a);
        }
      }
    }
    sO[nn * 100 + c] = a;
  }

  // ---------------- attention: this lane's row vs all 128 keys ----------------
  float acc[24];
  #pragma unroll
  for (int j = 0; j < 24; ++j) acc[j] = 0.f;
  float l = 0.f;

  #pragma unroll 2
  for (int m = 0; m < NTOK; ++m) {
    const float4* kr = reinterpret_cast<const float4*>(sK + m * 96 + hc);
    float4 k0 = kr[0], k1 = kr[1], k2 = kr[2], k3 = kr[3], k4 = kr[4], k5 = kr[5];
    float s0 = qr[0]*k0.x + qr[1]*k0.y + qr[2]*k0.z + qr[3]*k0.w;
    float s1 = qr[4]*k1.x + qr[5]*k1.y + qr[6]*k1.z + qr[7]*k1.w;
    float s2 = qr[8]*k2.x + qr[9]*k2.y + qr[10]*k2.z + qr[11]*k2.w;
    float s3 = qr[12]*k3.x + qr[13]*k3.y + qr[14]*k3.z + qr[15]*k3.w;
    s0 += qr[16]*k4.x + qr[17]*k4.y + qr[18]*k4.z + qr[19]*k4.w;
    s1 += qr[20]*k5.x + qr[21]*k5.y + qr[22]*k5.z + qr[23]*k5.w;
    float s = (s0 + s1) + (s2 + s3);
    float p = __expf(s);   // scores ~N(0,0.25): no max-subtract needed
    l += p;
    const float4* vr = reinterpret_cast<const float4*>(sV + m * 96 + hc);
    float4 v0 = vr[0], v1 = vr[1], v2 = vr[2], v3 = vr[3], v4 = vr[4], v5 = vr[5];
    acc[0]  = fmaf(p, v0.x, acc[0]);  acc[1]  = fmaf(p, v0.y, acc[1]);
    acc[2]  = fmaf(p, v0.z, acc[2]);  acc[3]  = fmaf(p, v0.w, acc[3]);
    acc[4]  = fmaf(p, v1.x, acc[4]);  acc[5]  = fmaf(p, v1.y, acc[5]);
    acc[6]  = fmaf(p, v1.z, acc[6]);  acc[7]  = fmaf(p, v1.w, acc[7]);
    acc[8]  = fmaf(p, v2.x, acc[8]);  acc[9]  = fmaf(p, v2.y, acc[9]);
    acc[10] = fmaf(p, v2.z, acc[10]); acc[11] = fmaf(p, v2.w, acc[11]);
    acc[12] = fmaf(p, v3.x, acc[12]); acc[13] = fmaf(p, v3.y, acc[13]);
    acc[14] = fmaf(p, v3.z, acc[14]); acc[15] = fmaf(p, v3.w, acc[15]);
    acc[16] = fmaf(p, v4.x, acc[16]); acc[17] = fmaf(p, v4.y, acc[17]);
    acc[18] = fmaf(p, v4.z, acc[18]); acc[19] = fmaf(p, v4.w, acc[19]);
    acc[20] = fmaf(p, v5.x, acc[20]); acc[21] = fmaf(p, v5.y, acc[21]);
    acc[22] = fmaf(p, v5.z, acc[22]); acc[23] = fmaf(p, v5.w, acc[23]);
  }

  __syncthreads();   // lepe done, all K/V reads done

  // add attention result (softmax-normalized) into sO
  {
    float rl = 1.0f / l;
    float4* orow = reinterpret_cast<float4*>(sO + n * 100 + hc);
    #pragma unroll
    for (int j = 0; j < 6; ++j) {
      float4 o = orow[j];
      o.x += acc[j*4+0] * rl; o.y += acc[j*4+1] * rl;
      o.z += acc[j*4+2] * rl; o.w += acc[j*4+3] * rl;
      orow[j] = o;
    }
  }

  // stage transposed proj_w into dead K region (stride 100 over ci)
  for (int i = t; i < C_ * C_; i += NTHR) {
    int co = i / 96, ci = i - co * 96;
    sPWT[ci * 100 + co] = pw[i];
  }

  __syncthreads();   // sO complete, sPWT staged

  // ---------------- projection + bias + store ----------------
  {
    const int pn  = t & 127;           // token row
    const int cbk = (t >> 7) * 24;     // output channel block
    float accp[24];
    #pragma unroll
    for (int j = 0; j < 24; ++j) accp[j] = sPB[cbk + j];
    const float4* orow4 = reinterpret_cast<const float4*>(sO + pn * 100);
    #pragma unroll 2
    for (int ci4 = 0; ci4 < 24; ++ci4) {
      float4 a4 = orow4[ci4];
      #pragma unroll
      for (int jj = 0; jj < 4; ++jj) {
        int ci = ci4 * 4 + jj;
        float a = (jj == 0) ? a4.x : (jj == 1) ? a4.y : (jj == 2) ? a4.z : a4.w;
        const float4* wr = reinterpret_cast<const float4*>(sPWT + ci * 100 + cbk);
        float4 w0 = wr[0], w1 = wr[1], w2 = wr[2], w3 = wr[3], w4 = wr[4], w5 = wr[5];
        accp[0]  = fmaf(a, w0.x, accp[0]);  accp[1]  = fmaf(a, w0.y, accp[1]);
        accp[2]  = fmaf(a, w0.z, accp[2]);  accp[3]  = fmaf(a, w0.w, accp[3]);
        accp[4]  = fmaf(a, w1.x, accp[4]);  accp[5]  = fmaf(a, w1.y, accp[5]);
        accp[6]  = fmaf(a, w1.z, accp[6]);  accp[7]  = fmaf(a, w1.w, accp[7]);
        accp[8]  = fmaf(a, w2.x, accp[8]);  accp[9]  = fmaf(a, w2.y, accp[9]);
        accp[10] = fmaf(a, w2.z, accp[10]); accp[11] = fmaf(a, w2.w, accp[11]);
        accp[12] = fmaf(a, w3.x, accp[12]); accp[13] = fmaf(a, w3.y, accp[13]);
        accp[14] = fmaf(a, w3.z, accp[14]); accp[15] = fmaf(a, w3.w, accp[15]);
        accp[16] = fmaf(a, w4.x, accp[16]); accp[17] = fmaf(a, w4.y, accp[17]);
        accp[18] = fmaf(a, w4.z, accp[18]); accp[19] = fmaf(a, w4.w, accp[19]);
        accp[20] = fmaf(a, w5.x, accp[20]); accp[21] = fmaf(a, w5.y, accp[21]);
        accp[22] = fmaf(a, w5.z, accp[22]); accp[23] = fmaf(a, w5.w, accp[23]);
      }
    }
    float* op = out + (size_t)(b * D_ + d) * HWC + (pn >> 1) * WC
                    + (wq * 2 + (pn & 1)) * C_ + cbk;
    #pragma unroll
    for (int j = 0; j < 6; ++j) {
      float4 o4 = { accp[j*4+0], accp[j*4+1], accp[j*4+2], accp[j*4+3] };
      reinterpret_cast<float4*>(op)[j] = o4;
    }
  }
}

extern "C" void kernel_launch(void* const* d_in, const int* in_sizes, int n_in,
                              void* d_out, int out_size, void* d_ws, size_t ws_size,
                              hipStream_t stream) {
  const float* qkv = (const float*)d_in[0];
  const float* cw  = (const float*)d_in[1];
  const float* cb  = (const float*)d_in[2];
  const float* pw  = (const float*)d_in[3];
  const float* pb  = (const float*)d_in[4];
  float* out = (float*)d_out;

  const size_t shmem = LDS_FLOATS * sizeof(float);  // ~157 KB
  // Allow >64KB dynamic LDS (gfx950 has 160KB/CU). Idempotent, capture-safe.
  static bool attr_set = false;
  if (!attr_set) {
    (void)hipFuncSetAttribute((const void*)sst_attn_kernel,
                              hipFuncAttributeMaxDynamicSharedMemorySize,
                              (int)shmem);
    attr_set = true;
  }

  dim3 grid(512);
  dim3 block(NTHR);
  hipLaunchKernelGGL(sst_attn_kernel, grid, block, shmem, stream,
                     qkv, cw, cb, pw, pb, out);
}

// Round 2
// 143.607 us; speedup vs baseline: 2.2733x; 2.2733x over previous
//
#include <hip/hip_runtime.h>

// Problem constants
constexpr int D_ = 8, H_ = 64, W_ = 64, C_ = 96;
constexpr int WC    = W_ * C_;            // 6144
constexpr int HWC   = H_ * W_ * C_;       // 393216
constexpr int BDHWC = 2 * D_ * HWC;       // 6291456
constexpr float SCALE = 0.10206207261596577f;  // (384/4)^-0.5

// ======================= Kernel A: per-(window,head) attention =======================
// grid 2048 = 512 windows x 4 heads, block 128 (2 waves). LDS 24KB -> 6 blocks/CU.
// Writes softmax(QK^T)V (head slice) into d_out (b,d,h,w,c) layout, unprojected.
__global__ void __launch_bounds__(128, 3)
attn_kernel(const float* __restrict__ qkv, float* __restrict__ out) {
  __shared__ float sK[128 * 24];
  __shared__ float sV[128 * 24];

  const int t    = threadIdx.x;
  const int bid  = blockIdx.x;
  const int head = bid & 3;
  const int nw   = bid >> 2;
  const int wq   = nw & 31;
  const int d    = (nw >> 5) & 7;
  const int b    = nw >> 8;
  const int hc   = head * 24;

  const float* qpl = qkv + (size_t)(b * 8 + d) * HWC;
  const float* kpl = qpl + BDHWC;
  const float* vpl = kpl + BDHWC;

  // ---- stage K,V head slices: 768 float4 each, 6 per thread ----
  {
    float4* k4 = reinterpret_cast<float4*>(sK);
    float4* v4 = reinterpret_cast<float4*>(sV);
    #pragma unroll
    for (int it = 0; it < 6; ++it) {
      int idx = t + it * 128;
      int tok = idx / 6, cj = idx - tok * 6;
      int g = (tok >> 1) * WC + (wq * 2 + (tok & 1)) * 96 + hc + cj * 4;
      k4[idx] = *reinterpret_cast<const float4*>(kpl + g);
      v4[idx] = *reinterpret_cast<const float4*>(vpl + g);
    }
  }

  // ---- this lane's q row ----
  const int n  = t;                                       // token 0..127
  const int tg = (n >> 1) * WC + (wq * 2 + (n & 1)) * 96 + hc;
  float qr[24];
  {
    const float4* q4 = reinterpret_cast<const float4*>(qpl + tg);
    #pragma unroll
    for (int j = 0; j < 6; ++j) {
      float4 x = q4[j];
      qr[4*j+0] = x.x * SCALE; qr[4*j+1] = x.y * SCALE;
      qr[4*j+2] = x.z * SCALE; qr[4*j+3] = x.w * SCALE;
    }
  }

  __syncthreads();

  // ---- attention over 128 keys (wave-uniform broadcast LDS reads) ----
  float acc[24];
  #pragma unroll
  for (int j = 0; j < 24; ++j) acc[j] = 0.f;
  float l = 0.f;

  #pragma unroll 2
  for (int m = 0; m < 128; ++m) {
    const float4* kr = reinterpret_cast<const float4*>(sK + m * 24);
    float4 k0 = kr[0], k1 = kr[1], k2 = kr[2], k3 = kr[3], k4 = kr[4], k5 = kr[5];
    float s0 = qr[0]*k0.x + qr[1]*k0.y + qr[2]*k0.z + qr[3]*k0.w;
    float s1 = qr[4]*k1.x + qr[5]*k1.y + qr[6]*k1.z + qr[7]*k1.w;
    float s2 = qr[8]*k2.x + qr[9]*k2.y + qr[10]*k2.z + qr[11]*k2.w;
    float s3 = qr[12]*k3.x + qr[13]*k3.y + qr[14]*k3.z + qr[15]*k3.w;
    s0 += qr[16]*k4.x + qr[17]*k4.y + qr[18]*k4.z + qr[19]*k4.w;
    s1 += qr[20]*k5.x + qr[21]*k5.y + qr[22]*k5.z + qr[23]*k5.w;
    float p = __expf((s0 + s1) + (s2 + s3));   // scores ~N(0,1): no max needed
    l += p;
    const float4* vr = reinterpret_cast<const float4*>(sV + m * 24);
    float4 v0 = vr[0], v1 = vr[1], v2 = vr[2], v3 = vr[3], v4 = vr[4], v5 = vr[5];
    acc[0]  = fmaf(p, v0.x, acc[0]);  acc[1]  = fmaf(p, v0.y, acc[1]);
    acc[2]  = fmaf(p, v0.z, acc[2]);  acc[3]  = fmaf(p, v0.w, acc[3]);
    acc[4]  = fmaf(p, v1.x, acc[4]);  acc[5]  = fmaf(p, v1.y, acc[5]);
    acc[6]  = fmaf(p, v1.z, acc[6]);  acc[7]  = fmaf(p, v1.w, acc[7]);
    acc[8]  = fmaf(p, v2.x, acc[8]);  acc[9]  = fmaf(p, v2.y, acc[9]);
    acc[10] = fmaf(p, v2.z, acc[10]); acc[11] = fmaf(p, v2.w, acc[11]);
    acc[12] = fmaf(p, v3.x, acc[12]); acc[13] = fmaf(p, v3.y, acc[13]);
    acc[14] = fmaf(p, v3.z, acc[14]); acc[15] = fmaf(p, v3.w, acc[15]);
    acc[16] = fmaf(p, v4.x, acc[16]); acc[17] = fmaf(p, v4.y, acc[17]);
    acc[18] = fmaf(p, v4.z, acc[18]); acc[19] = fmaf(p, v4.w, acc[19]);
    acc[20] = fmaf(p, v5.x, acc[20]); acc[21] = fmaf(p, v5.y, acc[21]);
    acc[22] = fmaf(p, v5.z, acc[22]); acc[23] = fmaf(p, v5.w, acc[23]);
  }

  // ---- write normalized result ----
  {
    float rl = 1.0f / l;
    float* op = out + (size_t)(b * 8 + d) * HWC + tg;
    #pragma unroll
    for (int j = 0; j < 6; ++j) {
      float4 o = { acc[4*j+0]*rl, acc[4*j+1]*rl, acc[4*j+2]*rl, acc[4*j+3]*rl };
      reinterpret_cast<float4*>(op)[j] = o;
    }
  }
}

// ======================= Kernel B: LePE + projection (in-place on d_out) =============
// grid 1024 = (b,d,h), block 256. Each block owns 64 tokens (all w of one h-row).
// LDS: sA[64][100] + sPWT[96][96] + sCW[27][96] + biases = 73.6KB -> 2 blocks/CU.
constexpr int OFFB_A   = 0;        // 6400 floats (stride 100)
constexpr int OFFB_PWT = 6400;     // 9216
constexpr int OFFB_CW  = 15616;    // 2592 ([tap][c])
constexpr int OFFB_CB  = 18208;    // 96
constexpr int OFFB_PB  = 18304;    // 96
constexpr int LDSB_FLOATS = 18400; // 73,600 bytes

__global__ void __launch_bounds__(256, 2)
lepe_proj_kernel(const float* __restrict__ qkv, const float* __restrict__ cw,
                 const float* __restrict__ cbias, const float* __restrict__ pw,
                 const float* __restrict__ pb, float* __restrict__ io) {
  extern __shared__ float lds[];
  float* sA   = lds + OFFB_A;
  float* sPWT = lds + OFFB_PWT;
  float* sCW  = lds + OFFB_CW;
  float* sCB  = lds + OFFB_CB;
  float* sPB  = lds + OFFB_PB;

  const int t   = threadIdx.x;
  const int bid = blockIdx.x;
  const int h   = bid & 63;
  const int d   = (bid >> 6) & 7;
  const int b   = bid >> 9;

  float* iop = io + (size_t)(b * 8 + d) * HWC + h * WC;          // 64 tokens x 96
  const float* vbatch = qkv + 2 * (size_t)BDHWC + (size_t)b * 8 * HWC;

  // ---- stage attention rows (read-before-overwrite), linear->stride100 ----
  {
    const float4* src = reinterpret_cast<const float4*>(iop);
    float4* dst = reinterpret_cast<float4*>(sA);
    #pragma unroll
    for (int it = 0; it < 6; ++it) {
      int idx = t + it * 256;                // 1536 float4
      int tok = idx / 24, c4 = idx - tok * 24;
      dst[tok * 25 + c4] = src[idx];
    }
  }
  // ---- stage proj weight transposed: sPWT[ci*96+co] = pw[co*96+ci] ----
  {
    #pragma unroll
    for (int it = 0; it < 9; ++it) {
      int idx = t + it * 256;                // 2304 slots
      int co = idx % 96, ci4 = idx / 96;
      float4 x = *reinterpret_cast<const float4*>(pw + co * 96 + ci4 * 4);
      sPWT[(ci4*4+0)*96 + co] = x.x;
      sPWT[(ci4*4+1)*96 + co] = x.y;
      sPWT[(ci4*4+2)*96 + co] = x.z;
      sPWT[(ci4*4+3)*96 + co] = x.w;
    }
  }
  // ---- stage conv weights transposed [tap][c], biases ----
  for (int idx = t; idx < 2592; idx += 256) {
    int c = idx / 27, tap = idx - c * 27;
    sCW[tap * 96 + c] = cw[idx];
  }
  if (t < 96) { sCB[t] = cbias[t]; sPB[t] = pb[t]; }
  __syncthreads();

  const int tt  = t >> 2;          // token (= w), 0..63
  const int cbk = (t & 3) * 24;    // channel block

  // ---- LePE for (token tt, channels cbk..cbk+23), add into sA ----
  float lep[24];
  {
    const float4* c4 = reinterpret_cast<const float4*>(sCB + cbk);
    #pragma unroll
    for (int j = 0; j < 6; ++j) {
      float4 x = c4[j];
      lep[4*j+0] = x.x; lep[4*j+1] = x.y; lep[4*j+2] = x.z; lep[4*j+3] = x.w;
    }
  }
  #pragma unroll
  for (int dd = 0; dd < 3; ++dd) {
    int zd = d + dd - 1;
    if (zd < 0 || zd >= D_) continue;          // block-uniform
    #pragma unroll
    for (int dh = 0; dh < 3; ++dh) {
      int zh = h + dh - 1;
      if (zh < 0 || zh >= H_) continue;        // block-uniform
      const float* vb2 = vbatch + (size_t)zd * HWC + zh * WC;
      #pragma unroll
      for (int dw = 0; dw < 3; ++dw) {
        int zw = tt + dw - 1;
        if (zw >= 0 && zw < W_) {              // diverges only on 2 edge lanes
          const float4* vp = reinterpret_cast<const float4*>(vb2 + zw * 96 + cbk);
          const float4* wp = reinterpret_cast<const float4*>(sCW + (dd*9+dh*3+dw) * 96 + cbk);
          #pragma unroll
          for (int j = 0; j < 6; ++j) {
            float4 v = vp[j], w = wp[j];
            lep[4*j+0] = fmaf(v.x, w.x, lep[4*j+0]);
            lep[4*j+1] = fmaf(v.y, w.y, lep[4*j+1]);
            lep[4*j+2] = fmaf(v.z, w.z, lep[4*j+2]);
            lep[4*j+3] = fmaf(v.w, w.w, lep[4*j+3]);
          }
        }
      }
    }
  }
  {
    float4* dst = reinterpret_cast<float4*>(sA + tt * 100 + cbk);
    #pragma unroll
    for (int j = 0; j < 6; ++j) {
      float4 o = dst[j];
      o.x += lep[4*j+0]; o.y += lep[4*j+1]; o.z += lep[4*j+2]; o.w += lep[4*j+3];
      dst[j] = o;
    }
  }
  __syncthreads();

  // ---- projection: out[tt][cbk+j] = sum_ci sA[tt][ci] * pw[cbk+j][ci] + pb ----
  float accp[24];
  {
    const float4* p4 = reinterpret_cast<const float4*>(sPB + cbk);
    #pragma unroll
    for (int j = 0; j < 6; ++j) {
      float4 x = p4[j];
      accp[4*j+0] = x.x; accp[4*j+1] = x.y; accp[4*j+2] = x.z; accp[4*j+3] = x.w;
    }
  }
  const float4* a4p = reinterpret_cast<const float4*>(sA + tt * 100);
  #pragma unroll 2
  for (int ci4 = 0; ci4 < 24; ++ci4) {
    float4 a4 = a4p[ci4];
    #pragma unroll
    for (int jj = 0; jj < 4; ++jj) {
      float a = (jj == 0) ? a4.x : (jj == 1) ? a4.y : (jj == 2) ? a4.z : a4.w;
      const float4* wr = reinterpret_cast<const float4*>(sPWT + (ci4*4+jj)*96 + cbk);
      float4 w0 = wr[0], w1 = wr[1], w2 = wr[2], w3 = wr[3], w4 = wr[4], w5 = wr[5];
      accp[0]  = fmaf(a, w0.x, accp[0]);  accp[1]  = fmaf(a, w0.y, accp[1]);
      accp[2]  = fmaf(a, w0.z, accp[2]);  accp[3]  = fmaf(a, w0.w, accp[3]);
      accp[4]  = fmaf(a, w1.x, accp[4]);  accp[5]  = fmaf(a, w1.y, accp[5]);
      accp[6]  = fmaf(a, w1.z, accp[6]);  accp[7]  = fmaf(a, w1.w, accp[7]);
      accp[8]  = fmaf(a, w2.x, accp[8]);  accp[9]  = fmaf(a, w2.y, accp[9]);
      accp[10] = fmaf(a, w2.z, accp[10]); accp[11] = fmaf(a, w2.w, accp[11]);
      accp[12] = fmaf(a, w3.x, accp[12]); accp[13] = fmaf(a, w3.y, accp[13]);
      accp[14] = fmaf(a, w3.z, accp[14]); accp[15] = fmaf(a, w3.w, accp[15]);
      accp[16] = fmaf(a, w4.x, accp[16]); accp[17] = fmaf(a, w4.y, accp[17]);
      accp[18] = fmaf(a, w4.z, accp[18]); accp[19] = fmaf(a, w4.w, accp[19]);
      accp[20] = fmaf(a, w5.x, accp[20]); accp[21] = fmaf(a, w5.y, accp[21]);
      accp[22] = fmaf(a, w5.z, accp[22]); accp[23] = fmaf(a, w5.w, accp[23]);
    }
  }
  {
    float* op = iop + tt * 96 + cbk;
    #pragma unroll
    for (int j = 0; j < 6; ++j) {
      float4 o = { accp[4*j+0], accp[4*j+1], accp[4*j+2], accp[4*j+3] };
      reinterpret_cast<float4*>(op)[j] = o;
    }
  }
}

extern "C" void kernel_launch(void* const* d_in, const int* in_sizes, int n_in,
                              void* d_out, int out_size, void* d_ws, size_t ws_size,
                              hipStream_t stream) {
  const float* qkv = (const float*)d_in[0];
  const float* cw  = (const float*)d_in[1];
  const float* cb  = (const float*)d_in[2];
  const float* pw  = (const float*)d_in[3];
  const float* pb  = (const float*)d_in[4];
  float* out = (float*)d_out;

  static bool attr_set = false;
  if (!attr_set) {
    (void)hipFuncSetAttribute((const void*)lepe_proj_kernel,
                              hipFuncAttributeMaxDynamicSharedMemorySize,
                              (int)(LDSB_FLOATS * sizeof(float)));
    attr_set = true;
  }

  hipLaunchKernelGGL(attn_kernel, dim3(2048), dim3(128), 0, stream, qkv, out);
  hipLaunchKernelGGL(lepe_proj_kernel, dim3(1024), dim3(256),
                     LDSB_FLOATS * sizeof(float), stream,
                     qkv, cw, cb, pw, pb, out);
}

// Round 3
// 98.574 us; speedup vs baseline: 3.3118x; 1.4568x over previous
//
#include <hip/hip_runtime.h>
#include <hip/hip_bf16.h>

constexpr int D_ = 8, H_ = 64, W_ = 64, C_ = 96;
constexpr int WC    = W_ * C_;            // 6144
constexpr int HWC   = H_ * W_ * C_;       // 393216
constexpr int BDHWC = 2 * D_ * HWC;       // 6291456
constexpr float SCALE = 0.10206207261596577f;  // (384/4)^-0.5

typedef __attribute__((ext_vector_type(4))) float f32x4;
typedef __attribute__((ext_vector_type(8))) short s16x8;

__device__ inline ushort f2bf(float x) {
  union { __hip_bfloat16 h; ushort u; } c;
  c.h = __float2bfloat16(x);
  return c.u;
}

// ================= Kernel A: MFMA attention per (window, head) =================
// grid 2048, block 256 (4 waves). Writes unprojected softmax(QK^T)V to d_out.
constexpr int QSTR = 40;    // halfword stride for sQ/sK rows (80B, 16B-mult)
constexpr int PSTR = 136;   // halfword stride for sP/sVt rows (272B, 16B-mult)
constexpr int OFF_Q  = 0;             // 128*40 = 5120 hw
constexpr int OFF_K  = 5120;          // 5120 hw
constexpr int OFF_VT = 10240;         // 32*136 = 4352 hw
constexpr int OFF_P  = 14592;         // 128*136 = 17408 hw
constexpr int LDS_HW = 32000;         // 64000 B static

__global__ void __launch_bounds__(256, 2)
attn_mfma_kernel(const float* __restrict__ qkv, float* __restrict__ out) {
  __shared__ ushort sH[LDS_HW];
  ushort* sQ  = sH + OFF_Q;
  ushort* sK  = sH + OFF_K;
  ushort* sVt = sH + OFF_VT;
  ushort* sP  = sH + OFF_P;

  const int t    = threadIdx.x;
  const int bid  = blockIdx.x;
  const int head = bid & 3;
  const int nw   = bid >> 2;
  const int wq   = nw & 31;
  const int d    = (nw >> 5) & 7;
  const int b    = nw >> 8;
  const int hc   = head * 24;

  const float* qpl = qkv + (size_t)(b * 8 + d) * HWC;
  const float* kpl = qpl + BDHWC;
  const float* vpl = kpl + BDHWC;

  // ---- zero pads: sQ/sK cols 24..39 (k-pad), sVt rows 24..31 (channel pad) ----
  {
    const s16x8 Z = {0, 0, 0, 0, 0, 0, 0, 0};
    int row = t >> 1, col = 24 + (t & 1) * 8;
    *reinterpret_cast<s16x8*>(&sQ[row * QSTR + col]) = Z;
    *reinterpret_cast<s16x8*>(&sK[row * QSTR + col]) = Z;
    if (t < 136) *reinterpret_cast<s16x8*>(&sVt[24 * PSTR + t * 8]) = Z;
  }

  // ---- stage Q,K row-major bf16; V transposed bf16 ----
  #pragma unroll
  for (int it = 0; it < 3; ++it) {
    int idx = t + it * 256;                 // 768 float4-groups
    int tok = idx / 6, c4 = (idx - tok * 6) * 4;
    int g = (tok >> 1) * WC + (wq * 2 + (tok & 1)) * 96 + hc + c4;
    float4 qv = *reinterpret_cast<const float4*>(qpl + g);
    float4 kv = *reinterpret_cast<const float4*>(kpl + g);
    float4 vv = *reinterpret_cast<const float4*>(vpl + g);
    ushort4 qh = { f2bf(qv.x * SCALE), f2bf(qv.y * SCALE),
                   f2bf(qv.z * SCALE), f2bf(qv.w * SCALE) };
    ushort4 kh = { f2bf(kv.x), f2bf(kv.y), f2bf(kv.z), f2bf(kv.w) };
    *reinterpret_cast<ushort4*>(&sQ[tok * QSTR + c4]) = qh;
    *reinterpret_cast<ushort4*>(&sK[tok * QSTR + c4]) = kh;
    sVt[(c4 + 0) * PSTR + tok] = f2bf(vv.x);
    sVt[(c4 + 1) * PSTR + tok] = f2bf(vv.y);
    sVt[(c4 + 2) * PSTR + tok] = f2bf(vv.z);
    sVt[(c4 + 3) * PSTR + tok] = f2bf(vv.w);
  }
  __syncthreads();

  const int wv = t >> 6, lane = t & 63;
  const int lr = lane & 15;          // row-in-block (A) / col (B,C)
  const int lg = lane >> 4;          // k-group / row-group
  const int r0 = (2 * wv) * 16;      // this wave's two 16-row blocks
  const int r1 = (2 * wv + 1) * 16;

  // ---- S = Q K^T : 16 MFMAs per wave ----
  f32x4 accS[2][8];
  #pragma unroll
  for (int i = 0; i < 2; ++i)
    #pragma unroll
    for (int j = 0; j < 8; ++j) accS[i][j] = f32x4{0.f, 0.f, 0.f, 0.f};

  {
    s16x8 a0 = *reinterpret_cast<const s16x8*>(&sQ[(r0 + lr) * QSTR + lg * 8]);
    s16x8 a1 = *reinterpret_cast<const s16x8*>(&sQ[(r1 + lr) * QSTR + lg * 8]);
    #pragma unroll
    for (int nb = 0; nb < 8; ++nb) {
      s16x8 bb = *reinterpret_cast<const s16x8*>(&sK[(nb * 16 + lr) * QSTR + lg * 8]);
      accS[0][nb] = __builtin_amdgcn_mfma_f32_16x16x32_bf16(a0, bb, accS[0][nb], 0, 0, 0);
      accS[1][nb] = __builtin_amdgcn_mfma_f32_16x16x32_bf16(a1, bb, accS[1][nb], 0, 0, 0);
    }
  }

  // ---- softmax (f32): exp in place, row sums via 16-lane shfl ----
  float rsum[2][4];
  #pragma unroll
  for (int rb = 0; rb < 2; ++rb) {
    #pragma unroll
    for (int r = 0; r < 4; ++r) {
      float s = 0.f;
      #pragma unroll
      for (int nb = 0; nb < 8; ++nb) {
        float e = __expf(accS[rb][nb][r]);   // scores ~N(0,0.25): no max needed
        accS[rb][nb][r] = e;
        s += e;
      }
      s += __shfl_xor(s, 1); s += __shfl_xor(s, 2);
      s += __shfl_xor(s, 4); s += __shfl_xor(s, 8);
      rsum[rb][r] = s;
    }
  }

  // ---- write P (bf16) for PV A-frags ----
  #pragma unroll
  for (int rb = 0; rb < 2; ++rb)
    #pragma unroll
    for (int nb = 0; nb < 8; ++nb)
      #pragma unroll
      for (int r = 0; r < 4; ++r)
        sP[((2 * wv + rb) * 16 + lg * 4 + r) * PSTR + nb * 16 + lr] =
            f2bf(accS[rb][nb][r]);
  __syncthreads();

  // ---- O = P V : 16 MFMAs per wave ----
  f32x4 accO[2][2];
  #pragma unroll
  for (int i = 0; i < 2; ++i)
    #pragma unroll
    for (int j = 0; j < 2; ++j) accO[i][j] = f32x4{0.f, 0.f, 0.f, 0.f};

  #pragma unroll
  for (int kb = 0; kb < 4; ++kb) {
    s16x8 pa0 = *reinterpret_cast<const s16x8*>(&sP[(r0 + lr) * PSTR + kb * 32 + lg * 8]);
    s16x8 pa1 = *reinterpret_cast<const s16x8*>(&sP[(r1 + lr) * PSTR + kb * 32 + lg * 8]);
    s16x8 vb0 = *reinterpret_cast<const s16x8*>(&sVt[lr * PSTR + kb * 32 + lg * 8]);
    s16x8 vb1 = *reinterpret_cast<const s16x8*>(&sVt[(16 + lr) * PSTR + kb * 32 + lg * 8]);
    accO[0][0] = __builtin_amdgcn_mfma_f32_16x16x32_bf16(pa0, vb0, accO[0][0], 0, 0, 0);
    accO[0][1] = __builtin_amdgcn_mfma_f32_16x16x32_bf16(pa0, vb1, accO[0][1], 0, 0, 0);
    accO[1][0] = __builtin_amdgcn_mfma_f32_16x16x32_bf16(pa1, vb0, accO[1][0], 0, 0, 0);
    accO[1][1] = __builtin_amdgcn_mfma_f32_16x16x32_bf16(pa1, vb1, accO[1][1], 0, 0, 0);
  }

  // ---- epilogue: normalize, store ----
  float* opl = out + (size_t)(b * 8 + d) * HWC;
  #pragma unroll
  for (int rb = 0; rb < 2; ++rb) {
    #pragma unroll
    for (int r = 0; r < 4; ++r) {
      int tok = (2 * wv + rb) * 16 + lg * 4 + r;
      int g = (tok >> 1) * WC + (wq * 2 + (tok & 1)) * 96 + hc;
      float inv = 1.0f / rsum[rb][r];
      opl[g + lr] = accO[rb][0][r] * inv;
      if (lr < 8) opl[g + 16 + lr] = accO[rb][1][r] * inv;
    }
  }
}

// ================= Kernel B: LePE + projection (unchanged, in-place) =================
constexpr int OFFB_A   = 0;
constexpr int OFFB_PWT = 6400;
constexpr int OFFB_CW  = 15616;
constexpr int OFFB_CB  = 18208;
constexpr int OFFB_PB  = 18304;
constexpr int LDSB_FLOATS = 18400;

__global__ void __launch_bounds__(256, 2)
lepe_proj_kernel(const float* __restrict__ qkv, const float* __restrict__ cw,
                 const float* __restrict__ cbias, const float* __restrict__ pw,
                 const float* __restrict__ pb, float* __restrict__ io) {
  extern __shared__ float lds[];
  float* sA   = lds + OFFB_A;
  float* sPWT = lds + OFFB_PWT;
  float* sCW  = lds + OFFB_CW;
  float* sCB  = lds + OFFB_CB;
  float* sPB  = lds + OFFB_PB;

  const int t   = threadIdx.x;
  const int bid = blockIdx.x;
  const int h   = bid & 63;
  const int d   = (bid >> 6) & 7;
  const int b   = bid >> 9;

  float* iop = io + (size_t)(b * 8 + d) * HWC + h * WC;
  const float* vbatch = qkv + 2 * (size_t)BDHWC + (size_t)b * 8 * HWC;

  {
    const float4* src = reinterpret_cast<const float4*>(iop);
    float4* dst = reinterpret_cast<float4*>(sA);
    #pragma unroll
    for (int it = 0; it < 6; ++it) {
      int idx = t + it * 256;
      int tok = idx / 24, c4 = idx - tok * 24;
      dst[tok * 25 + c4] = src[idx];
    }
  }
  {
    #pragma unroll
    for (int it = 0; it < 9; ++it) {
      int idx = t + it * 256;
      int co = idx % 96, ci4 = idx / 96;
      float4 x = *reinterpret_cast<const float4*>(pw + co * 96 + ci4 * 4);
      sPWT[(ci4*4+0)*96 + co] = x.x;
      sPWT[(ci4*4+1)*96 + co] = x.y;
      sPWT[(ci4*4+2)*96 + co] = x.z;
      sPWT[(ci4*4+3)*96 + co] = x.w;
    }
  }
  for (int idx = t; idx < 2592; idx += 256) {
    int c = idx / 27, tap = idx - c * 27;
    sCW[tap * 96 + c] = cw[idx];
  }
  if (t < 96) { sCB[t] = cbias[t]; sPB[t] = pb[t]; }
  __syncthreads();

  const int tt  = t >> 2;
  const int cbk = (t & 3) * 24;

  float lep[24];
  {
    const float4* c4 = reinterpret_cast<const float4*>(sCB + cbk);
    #pragma unroll
    for (int j = 0; j < 6; ++j) {
      float4 x = c4[j];
      lep[4*j+0] = x.x; lep[4*j+1] = x.y; lep[4*j+2] = x.z; lep[4*j+3] = x.w;
    }
  }
  #pragma unroll
  for (int dd = 0; dd < 3; ++dd) {
    int zd = d + dd - 1;
    if (zd < 0 || zd >= D_) continue;
    #pragma unroll
    for (int dh = 0; dh < 3; ++dh) {
      int zh = h + dh - 1;
      if (zh < 0 || zh >= H_) continue;
      const float* vb2 = vbatch + (size_t)zd * HWC + zh * WC;
      #pragma unroll
      for (int dw = 0; dw < 3; ++dw) {
        int zw = tt + dw - 1;
        if (zw >= 0 && zw < W_) {
          const float4* vp = reinterpret_cast<const float4*>(vb2 + zw * 96 + cbk);
          const float4* wp = reinterpret_cast<const float4*>(sCW + (dd*9+dh*3+dw) * 96 + cbk);
          #pragma unroll
          for (int j = 0; j < 6; ++j) {
            float4 v = vp[j], w = wp[j];
            lep[4*j+0] = fmaf(v.x, w.x, lep[4*j+0]);
            lep[4*j+1] = fmaf(v.y, w.y, lep[4*j+1]);
            lep[4*j+2] = fmaf(v.z, w.z, lep[4*j+2]);
            lep[4*j+3] = fmaf(v.w, w.w, lep[4*j+3]);
          }
        }
      }
    }
  }
  {
    float4* dst = reinterpret_cast<float4*>(sA + tt * 100 + cbk);
    #pragma unroll
    for (int j = 0; j < 6; ++j) {
      float4 o = dst[j];
      o.x += lep[4*j+0]; o.y += lep[4*j+1]; o.z += lep[4*j+2]; o.w += lep[4*j+3];
      dst[j] = o;
    }
  }
  __syncthreads();

  float accp[24];
  {
    const float4* p4 = reinterpret_cast<const float4*>(sPB + cbk);
    #pragma unroll
    for (int j = 0; j < 6; ++j) {
      float4 x = p4[j];
      accp[4*j+0] = x.x; accp[4*j+1] = x.y; accp[4*j+2] = x.z; accp[4*j+3] = x.w;
    }
  }
  const float4* a4p = reinterpret_cast<const float4*>(sA + tt * 100);
  #pragma unroll 2
  for (int ci4 = 0; ci4 < 24; ++ci4) {
    float4 a4 = a4p[ci4];
    #pragma unroll
    for (int jj = 0; jj < 4; ++jj) {
      float a = (jj == 0) ? a4.x : (jj == 1) ? a4.y : (jj == 2) ? a4.z : a4.w;
      const float4* wr = reinterpret_cast<const float4*>(sPWT + (ci4*4+jj)*96 + cbk);
      float4 w0 = wr[0], w1 = wr[1], w2 = wr[2], w3 = wr[3], w4 = wr[4], w5 = wr[5];
      accp[0]  = fmaf(a, w0.x, accp[0]);  accp[1]  = fmaf(a, w0.y, accp[1]);
      accp[2]  = fmaf(a, w0.z, accp[2]);  accp[3]  = fmaf(a, w0.w, accp[3]);
      accp[4]  = fmaf(a, w1.x, accp[4]);  accp[5]  = fmaf(a, w1.y, accp[5]);
      accp[6]  = fmaf(a, w1.z, accp[6]);  accp[7]  = fmaf(a, w1.w, accp[7]);
      accp[8]  = fmaf(a, w2.x, accp[8]);  accp[9]  = fmaf(a, w2.y, accp[9]);
      accp[10] = fmaf(a, w2.z, accp[10]); accp[11] = fmaf(a, w2.w, accp[11]);
      accp[12] = fmaf(a, w3.x, accp[12]); accp[13] = fmaf(a, w3.y, accp[13]);
      accp[14] = fmaf(a, w3.z, accp[14]); accp[15] = fmaf(a, w3.w, accp[15]);
      accp[16] = fmaf(a, w4.x, accp[16]); accp[17] = fmaf(a, w4.y, accp[17]);
      accp[18] = fmaf(a, w4.z, accp[18]); accp[19] = fmaf(a, w4.w, accp[19]);
      accp[20] = fmaf(a, w5.x, accp[20]); accp[21] = fmaf(a, w5.y, accp[21]);
      accp[22] = fmaf(a, w5.z, accp[22]); accp[23] = fmaf(a, w5.w, accp[23]);
    }
  }
  {
    float* op = iop + tt * 96 + cbk;
    #pragma unroll
    for (int j = 0; j < 6; ++j) {
      float4 o = { accp[4*j+0], accp[4*j+1], accp[4*j+2], accp[4*j+3] };
      reinterpret_cast<float4*>(op)[j] = o;
    }
  }
}

extern "C" void kernel_launch(void* const* d_in, const int* in_sizes, int n_in,
                              void* d_out, int out_size, void* d_ws, size_t ws_size,
                              hipStream_t stream) {
  const float* qkv = (const float*)d_in[0];
  const float* cw  = (const float*)d_in[1];
  const float* cb  = (const float*)d_in[2];
  const float* pw  = (const float*)d_in[3];
  const float* pb  = (const float*)d_in[4];
  float* out = (float*)d_out;

  static bool attr_set = false;
  if (!attr_set) {
    (void)hipFuncSetAttribute((const void*)lepe_proj_kernel,
                              hipFuncAttributeMaxDynamicSharedMemorySize,
                              (int)(LDSB_FLOATS * sizeof(float)));
    attr_set = true;
  }

  hipLaunchKernelGGL(attn_mfma_kernel, dim3(2048), dim3(256), 0, stream, qkv, out);
  hipLaunchKernelGGL(lepe_proj_kernel, dim3(1024), dim3(256),
                     LDSB_FLOATS * sizeof(float), stream,
                     qkv, cw, cb, pw, pb, out);
}

// Round 4
// 86.286 us; speedup vs baseline: 3.7834x; 1.1424x over previous
//
#include <hip/hip_runtime.h>
#include <hip/hip_bf16.h>

constexpr int D_ = 8, H_ = 64, W_ = 64, C_ = 96;
constexpr int WC    = W_ * C_;            // 6144
constexpr int HWC   = H_ * W_ * C_;       // 393216
constexpr int BDHWC = 2 * D_ * HWC;       // 6291456
constexpr float SCALE = 0.10206207261596577f;  // (384/4)^-0.5

typedef __attribute__((ext_vector_type(4))) float f32x4;
typedef __attribute__((ext_vector_type(8))) short s16x8;

__device__ inline ushort f2bf(float x) {
  union { __hip_bfloat16 h; ushort u; } c;
  c.h = __float2bfloat16(x);
  return c.u;
}

// ================= Kernel A: MFMA attention per (window, head) =================
// grid 2048, block 256 (4 waves). Writes unprojected softmax(QK^T)V to d_out.
constexpr int QSTR = 40;    // halfword stride for sQ/sK rows
constexpr int PSTR = 136;   // halfword stride for sP/sVt rows
constexpr int OFF_Q  = 0;
constexpr int OFF_K  = 5120;
constexpr int OFF_VT = 10240;
constexpr int OFF_P  = 14592;
constexpr int LDS_HW = 32000;         // 64000 B static

__global__ void __launch_bounds__(256, 2)
attn_mfma_kernel(const float* __restrict__ qkv, float* __restrict__ out) {
  __shared__ ushort sH[LDS_HW];
  ushort* sQ  = sH + OFF_Q;
  ushort* sK  = sH + OFF_K;
  ushort* sVt = sH + OFF_VT;
  ushort* sP  = sH + OFF_P;

  const int t    = threadIdx.x;
  const int bid  = blockIdx.x;
  const int head = bid & 3;
  const int nw   = bid >> 2;
  const int wq   = nw & 31;
  const int d    = (nw >> 5) & 7;
  const int b    = nw >> 8;
  const int hc   = head * 24;

  const float* qpl = qkv + (size_t)(b * 8 + d) * HWC;
  const float* kpl = qpl + BDHWC;
  const float* vpl = kpl + BDHWC;

  {
    const s16x8 Z = {0, 0, 0, 0, 0, 0, 0, 0};
    int row = t >> 1, col = 24 + (t & 1) * 8;
    *reinterpret_cast<s16x8*>(&sQ[row * QSTR + col]) = Z;
    *reinterpret_cast<s16x8*>(&sK[row * QSTR + col]) = Z;
    if (t < 136) *reinterpret_cast<s16x8*>(&sVt[24 * PSTR + t * 8]) = Z;
  }

  #pragma unroll
  for (int it = 0; it < 3; ++it) {
    int idx = t + it * 256;
    int tok = idx / 6, c4 = (idx - tok * 6) * 4;
    int g = (tok >> 1) * WC + (wq * 2 + (tok & 1)) * 96 + hc + c4;
    float4 qv = *reinterpret_cast<const float4*>(qpl + g);
    float4 kv = *reinterpret_cast<const float4*>(kpl + g);
    float4 vv = *reinterpret_cast<const float4*>(vpl + g);
    ushort4 qh = { f2bf(qv.x * SCALE), f2bf(qv.y * SCALE),
                   f2bf(qv.z * SCALE), f2bf(qv.w * SCALE) };
    ushort4 kh = { f2bf(kv.x), f2bf(kv.y), f2bf(kv.z), f2bf(kv.w) };
    *reinterpret_cast<ushort4*>(&sQ[tok * QSTR + c4]) = qh;
    *reinterpret_cast<ushort4*>(&sK[tok * QSTR + c4]) = kh;
    sVt[(c4 + 0) * PSTR + tok] = f2bf(vv.x);
    sVt[(c4 + 1) * PSTR + tok] = f2bf(vv.y);
    sVt[(c4 + 2) * PSTR + tok] = f2bf(vv.z);
    sVt[(c4 + 3) * PSTR + tok] = f2bf(vv.w);
  }
  __syncthreads();

  const int wv = t >> 6, lane = t & 63;
  const int lr = lane & 15;
  const int lg = lane >> 4;
  const int r0 = (2 * wv) * 16;
  const int r1 = (2 * wv + 1) * 16;

  f32x4 accS[2][8];
  #pragma unroll
  for (int i = 0; i < 2; ++i)
    #pragma unroll
    for (int j = 0; j < 8; ++j) accS[i][j] = f32x4{0.f, 0.f, 0.f, 0.f};

  {
    s16x8 a0 = *reinterpret_cast<const s16x8*>(&sQ[(r0 + lr) * QSTR + lg * 8]);
    s16x8 a1 = *reinterpret_cast<const s16x8*>(&sQ[(r1 + lr) * QSTR + lg * 8]);
    #pragma unroll
    for (int nb = 0; nb < 8; ++nb) {
      s16x8 bb = *reinterpret_cast<const s16x8*>(&sK[(nb * 16 + lr) * QSTR + lg * 8]);
      accS[0][nb] = __builtin_amdgcn_mfma_f32_16x16x32_bf16(a0, bb, accS[0][nb], 0, 0, 0);
      accS[1][nb] = __builtin_amdgcn_mfma_f32_16x16x32_bf16(a1, bb, accS[1][nb], 0, 0, 0);
    }
  }

  float rsum[2][4];
  #pragma unroll
  for (int rb = 0; rb < 2; ++rb) {
    #pragma unroll
    for (int r = 0; r < 4; ++r) {
      float s = 0.f;
      #pragma unroll
      for (int nb = 0; nb < 8; ++nb) {
        float e = __expf(accS[rb][nb][r]);
        accS[rb][nb][r] = e;
        s += e;
      }
      s += __shfl_xor(s, 1); s += __shfl_xor(s, 2);
      s += __shfl_xor(s, 4); s += __shfl_xor(s, 8);
      rsum[rb][r] = s;
    }
  }

  #pragma unroll
  for (int rb = 0; rb < 2; ++rb)
    #pragma unroll
    for (int nb = 0; nb < 8; ++nb)
      #pragma unroll
      for (int r = 0; r < 4; ++r)
        sP[((2 * wv + rb) * 16 + lg * 4 + r) * PSTR + nb * 16 + lr] =
            f2bf(accS[rb][nb][r]);
  __syncthreads();

  f32x4 accO[2][2];
  #pragma unroll
  for (int i = 0; i < 2; ++i)
    #pragma unroll
    for (int j = 0; j < 2; ++j) accO[i][j] = f32x4{0.f, 0.f, 0.f, 0.f};

  #pragma unroll
  for (int kb = 0; kb < 4; ++kb) {
    s16x8 pa0 = *reinterpret_cast<const s16x8*>(&sP[(r0 + lr) * PSTR + kb * 32 + lg * 8]);
    s16x8 pa1 = *reinterpret_cast<const s16x8*>(&sP[(r1 + lr) * PSTR + kb * 32 + lg * 8]);
    s16x8 vb0 = *reinterpret_cast<const s16x8*>(&sVt[lr * PSTR + kb * 32 + lg * 8]);
    s16x8 vb1 = *reinterpret_cast<const s16x8*>(&sVt[(16 + lr) * PSTR + kb * 32 + lg * 8]);
    accO[0][0] = __builtin_amdgcn_mfma_f32_16x16x32_bf16(pa0, vb0, accO[0][0], 0, 0, 0);
    accO[0][1] = __builtin_amdgcn_mfma_f32_16x16x32_bf16(pa0, vb1, accO[0][1], 0, 0, 0);
    accO[1][0] = __builtin_amdgcn_mfma_f32_16x16x32_bf16(pa1, vb0, accO[1][0], 0, 0, 0);
    accO[1][1] = __builtin_amdgcn_mfma_f32_16x16x32_bf16(pa1, vb1, accO[1][1], 0, 0, 0);
  }

  float* opl = out + (size_t)(b * 8 + d) * HWC;
  #pragma unroll
  for (int rb = 0; rb < 2; ++rb) {
    #pragma unroll
    for (int r = 0; r < 4; ++r) {
      int tok = (2 * wv + rb) * 16 + lg * 4 + r;
      int g = (tok >> 1) * WC + (wq * 2 + (tok & 1)) * 96 + hc;
      float inv = 1.0f / rsum[rb][r];
      opl[g + lr] = accO[rb][0][r] * inv;
      if (lr < 8) opl[g + 16 + lr] = accO[rb][1][r] * inv;
    }
  }
}

// ============ Kernel B: LePE (fp32 stencil) + MFMA bf16 projection, in-place ============
// grid 1024 = (b,d,h), block 256 (4 waves). LDS ~44KB -> 3 blocks/CU.
constexpr int WSTR = 104;   // halfword stride (208B)

__global__ void __launch_bounds__(256, 3)
lepe_proj_mfma_kernel(const float* __restrict__ qkv, const float* __restrict__ cw,
                      const float* __restrict__ cbias, const float* __restrict__ pw,
                      const float* __restrict__ pb, float* __restrict__ io) {
  __shared__ ushort sW[96 * WSTR];    // proj weight bf16, row co, contiguous ci
  __shared__ ushort sA[64 * WSTR];    // lepe+attn rows bf16
  __shared__ float  sCW[27 * 96];     // conv weights [tap][c]
  __shared__ float  sCB[96];
  __shared__ float  sPB[96];

  const int t   = threadIdx.x;
  const int bid = blockIdx.x;
  const int h   = bid & 63;
  const int d   = (bid >> 6) & 7;
  const int b   = bid >> 9;

  float* iop = io + (size_t)(b * 8 + d) * HWC + h * WC;          // 64 tokens x 96
  const float* vbatch = qkv + 2 * (size_t)BDHWC + (size_t)b * 8 * HWC;

  // ---- stage proj weight bf16 (pw rows are already B-frag k-major) ----
  #pragma unroll
  for (int it = 0; it < 9; ++it) {
    int idx = t + it * 256;                 // 2304 float4
    int co = idx / 24, c4 = (idx - co * 24) * 4;
    float4 x = *reinterpret_cast<const float4*>(pw + co * 96 + c4);
    ushort4 hx = { f2bf(x.x), f2bf(x.y), f2bf(x.z), f2bf(x.w) };
    *reinterpret_cast<ushort4*>(&sW[co * WSTR + c4]) = hx;
  }
  // ---- conv weights transposed [tap][c], biases ----
  for (int idx = t; idx < 2592; idx += 256) {
    int c = idx / 27, tap = idx - c * 27;
    sCW[tap * 96 + c] = cw[idx];
  }
  if (t < 96) { sCB[t] = cbias[t]; sPB[t] = pb[t]; }
  __syncthreads();

  const int tt  = t >> 2;          // token (= w)
  const int cbk = (t & 3) * 24;    // channel block

  // ---- LePE fp32 + add attn rows, store bf16 to sA ----
  float lep[24];
  {
    const float4* c4 = reinterpret_cast<const float4*>(sCB + cbk);
    #pragma unroll
    for (int j = 0; j < 6; ++j) {
      float4 x = c4[j];
      lep[4*j+0] = x.x; lep[4*j+1] = x.y; lep[4*j+2] = x.z; lep[4*j+3] = x.w;
    }
  }
  #pragma unroll
  for (int dd = 0; dd < 3; ++dd) {
    int zd = d + dd - 1;
    if (zd < 0 || zd >= D_) continue;          // block-uniform
    #pragma unroll
    for (int dh = 0; dh < 3; ++dh) {
      int zh = h + dh - 1;
      if (zh < 0 || zh >= H_) continue;        // block-uniform
      const float* vb2 = vbatch + (size_t)zd * HWC + zh * WC;
      #pragma unroll
      for (int dw = 0; dw < 3; ++dw) {
        int zw = tt + dw - 1;
        if (zw >= 0 && zw < W_) {
          const float4* vp = reinterpret_cast<const float4*>(vb2 + zw * 96 + cbk);
          const float4* wp = reinterpret_cast<const float4*>(sCW + (dd*9+dh*3+dw) * 96 + cbk);
          #pragma unroll
          for (int j = 0; j < 6; ++j) {
            float4 v = vp[j], w = wp[j];
            lep[4*j+0] = fmaf(v.x, w.x, lep[4*j+0]);
            lep[4*j+1] = fmaf(v.y, w.y, lep[4*j+1]);
            lep[4*j+2] = fmaf(v.z, w.z, lep[4*j+2]);
            lep[4*j+3] = fmaf(v.w, w.w, lep[4*j+3]);
          }
        }
      }
    }
  }
  {
    const float4* arow = reinterpret_cast<const float4*>(iop + tt * 96 + cbk);
    #pragma unroll
    for (int j = 0; j < 6; ++j) {
      float4 a = arow[j];
      ushort4 hx = { f2bf(lep[4*j+0] + a.x), f2bf(lep[4*j+1] + a.y),
                     f2bf(lep[4*j+2] + a.z), f2bf(lep[4*j+3] + a.w) };
      *reinterpret_cast<ushort4*>(&sA[tt * WSTR + cbk + j * 4]) = hx;
    }
  }
  __syncthreads();

  // ---- projection via MFMA: each wave owns 16 tokens ----
  const int wv = t >> 6, lane = t & 63;
  const int lr = lane & 15, lg = lane >> 4;

  f32x4 acc[6];
  #pragma unroll
  for (int cb = 0; cb < 6; ++cb) {
    float bv = sPB[cb * 16 + lr];
    acc[cb] = f32x4{bv, bv, bv, bv};
  }
  s16x8 afr[3];
  #pragma unroll
  for (int kb = 0; kb < 3; ++kb)
    afr[kb] = *reinterpret_cast<const s16x8*>(&sA[(wv * 16 + lr) * WSTR + kb * 32 + lg * 8]);
  #pragma unroll
  for (int kb = 0; kb < 3; ++kb) {
    #pragma unroll
    for (int cb = 0; cb < 6; ++cb) {
      s16x8 bfr = *reinterpret_cast<const s16x8*>(&sW[(cb * 16 + lr) * WSTR + kb * 32 + lg * 8]);
      acc[cb] = __builtin_amdgcn_mfma_f32_16x16x32_bf16(afr[kb], bfr, acc[cb], 0, 0, 0);
    }
  }

  // ---- store fp32 ----
  #pragma unroll
  for (int cb = 0; cb < 6; ++cb) {
    #pragma unroll
    for (int r = 0; r < 4; ++r) {
      int tok = wv * 16 + lg * 4 + r;
      iop[tok * 96 + cb * 16 + lr] = acc[cb][r];
    }
  }
}

extern "C" void kernel_launch(void* const* d_in, const int* in_sizes, int n_in,
                              void* d_out, int out_size, void* d_ws, size_t ws_size,
                              hipStream_t stream) {
  const float* qkv = (const float*)d_in[0];
  const float* cw  = (const float*)d_in[1];
  const float* cb  = (const float*)d_in[2];
  const float* pw  = (const float*)d_in[3];
  const float* pb  = (const float*)d_in[4];
  float* out = (float*)d_out;

  hipLaunchKernelGGL(attn_mfma_kernel, dim3(2048), dim3(256), 0, stream, qkv, out);
  hipLaunchKernelGGL(lepe_proj_mfma_kernel, dim3(1024), dim3(256), 0, stream,
                     qkv, cw, cb, pw, pb, out);
}